// Round 5
// baseline (392.750 us; speedup 1.0000x reference)
//
#include <hip/hip_runtime.h>
#include <stdint.h>

// out[bm,q,h] = sum_k s[bm,q,k] * v[bm,k,h]
// bm=64, QT=KVT=1024, H=64, fp32 in/out. Memory-bound: ~302 MB HBM => ~48us floor.
// R5: BARRIER-FREE K-loop. v^T half (512k x 64h bf16, 64 KB, XOR-swizzled) is
// staged to LDS once per phase; the K-loop itself has zero barriers, so every
// wave streams s independently (global->reg->cvt->MFMA) with a 2-deep register
// prefetch the compiler can pipeline (no vmcnt(0) drains left to defeat it).
// 512 thr x 512 blocks = whole grid co-resident (2 blocks/CU, 128 KB LDS/CU).

typedef __bf16   bf16x8 __attribute__((ext_vector_type(8)));
typedef float    f32x4  __attribute__((ext_vector_type(4)));
typedef uint32_t u32x4  __attribute__((ext_vector_type(4)));

#define QTDIM 1024
#define KVDIM 1024
#define HDIM  64
#define QTILE 128
#define THREADS 512
#define KHALF 512          // k-range per phase
#define VSTR  512          // LDS row stride (bf16 elems) = 1024 B; swizzle, no pad

// truncate two f32 to bf16, pack (hi<<16)|lo in one v_perm_b32
__device__ __forceinline__ uint32_t pack_bf16_2(float lo, float hi) {
    union { float f; uint32_t u; } a, b;
    a.f = lo; b.f = hi;
    return __builtin_amdgcn_perm(b.u, a.u, 0x07060302u);
}

// barrier with LDS visibility only (lgkmcnt); keeps global loads in flight
__device__ __forceinline__ void lds_barrier() {
    asm volatile("s_waitcnt lgkmcnt(0)\n\ts_barrier" ::: "memory");
}

__global__ __launch_bounds__(THREADS, 4) void svbmm_kernel(
    const float* __restrict__ s, const float* __restrict__ v, float* __restrict__ out)
{
    // v^T half-tile [h][k_local], bf16. 16-B granule g at row r lives at
    // g' = g ^ (r&7): banks spread uniformly for both the transpose-write
    // (lanes vary r) and the B-fragment read (lanes vary r, quad).
    __shared__ uint16_t vt_sm[HDIM * VSTR];   // 65536 B exactly

    const int tid = threadIdx.x;
    const int bm  = blockIdx.x;            // fast: q-tiles of bm share XCD bm%8
    const int q0  = blockIdx.y * QTILE;

    const float* sp = s   + ((size_t)bm * QTDIM + q0) * (size_t)KVDIM;
    const float* vp = v   + (size_t)bm * KVDIM * HDIM;
    float*       op = out + ((size_t)bm * QTDIM + q0) * (size_t)HDIM;

    const int wave = tid >> 6;   // 8 waves; wave owns q-rows [wave*16, wave*16+16)
    const int lane = tid & 63;
    const int lrow = lane & 15;
    const int quad = lane >> 4;

    // v staging: lane-per-h (256 B coalesced), 8 k-groups x 64 k
    const int vh = tid & 63;
    const int kg = tid >> 6;

    // A stream: lane (lrow,quad) reads s[wave*16+lrow][... + kk*32 + quad*8 + 0..8)
    const float* ap = sp + (wave * 16 + lrow) * KVDIM + quad * 8;

    f32x4 acc[4];
    #pragma unroll
    for (int nt = 0; nt < 4; ++nt) acc[nt] = (f32x4){0.f, 0.f, 0.f, 0.f};

    #pragma unroll 1
    for (int kh = 0; kh < 2; ++kh) {
        const float* abase = ap + kh * KHALF;

        // A prologue for tiles 0,1 of this phase — issued BEFORE staging so
        // they arrive while we stage v (they have no LDS dependency).
        float4 aA[4], aB[4];
        #pragma unroll
        for (int i = 0; i < 4; ++i) {
            const int off = (i >> 1) * 32 + (i & 1) * 4;
            aA[i] = *(const float4*)(abase + off);
            aB[i] = *(const float4*)(abase + 64 + off);
        }

        // protect LDS overwrite: all waves done READING previous half (lgkm only)
        if (kh) lds_barrier();

        // ---- stage v half: transpose + cvt, b128 writes, swizzled ----
        #pragma unroll
        for (int c = 0; c < 8; ++c) {
            const float* vb = vp + (size_t)(kh * KHALF + kg * 64 + c * 8) * HDIM + vh;
            float vr[8];
            #pragma unroll
            for (int j = 0; j < 8; ++j) vr[j] = vb[j * HDIM];
            u32x4 w;
            w[0] = pack_bf16_2(vr[0], vr[1]);
            w[1] = pack_bf16_2(vr[2], vr[3]);
            w[2] = pack_bf16_2(vr[4], vr[5]);
            w[3] = pack_bf16_2(vr[6], vr[7]);
            const int g = kg * 8 + c;
            *(u32x4*)&vt_sm[vh * VSTR + ((g ^ (vh & 7)) << 3)] = w;
        }
        lds_barrier();   // publish the half; ONLY barrier before next phase

        // ---- 8 tiles of BK=64: ZERO barriers, per-wave streaming ----
#define TILE(KT, AR)                                                            \
        do {                                                                    \
            bf16x8 afrag[2];                                                    \
            _Pragma("unroll")                                                   \
            for (int kk = 0; kk < 2; ++kk) {                                    \
                union { u32x4 u; bf16x8 b; } fa;                                \
                float4 lo = AR[kk * 2], hi = AR[kk * 2 + 1];                    \
                fa.u[0] = pack_bf16_2(lo.x, lo.y);                              \
                fa.u[1] = pack_bf16_2(lo.z, lo.w);                              \
                fa.u[2] = pack_bf16_2(hi.x, hi.y);                              \
                fa.u[3] = pack_bf16_2(hi.z, hi.w);                              \
                afrag[kk] = fa.b;                                               \
            }                                                                   \
            if ((KT) + 2 < 8) {                                                 \
                _Pragma("unroll")                                               \
                for (int i = 0; i < 4; ++i) {                                   \
                    const int off = (i >> 1) * 32 + (i & 1) * 4;                \
                    AR[i] = *(const float4*)(abase + ((KT) + 2) * 64 + off);    \
                }                                                               \
            }                                                                   \
            _Pragma("unroll")                                                   \
            for (int kk = 0; kk < 2; ++kk) {                                    \
                _Pragma("unroll")                                               \
                for (int nt = 0; nt < 4; ++nt) {                                \
                    const int row = nt * 16 + lrow;                             \
                    const int g   = (KT) * 8 + kk * 4 + quad;                   \
                    bf16x8 b = *(const bf16x8*)&vt_sm[row * VSTR + ((g ^ (row & 7)) << 3)]; \
                    acc[nt] = __builtin_amdgcn_mfma_f32_16x16x32_bf16(          \
                        afrag[kk], b, acc[nt], 0, 0, 0);                        \
                }                                                               \
            }                                                                   \
        } while (0)

        #pragma unroll
        for (int kt = 0; kt < 8; kt += 2) {
            TILE(kt,     aA);
            TILE(kt + 1, aB);
        }
#undef TILE
    }

    // epilogue: D layout row = quad*4 + r, col = lane&15 (m89/m91-verified)
    #pragma unroll
    for (int nt = 0; nt < 4; ++nt) {
        #pragma unroll
        for (int r = 0; r < 4; ++r) {
            const int row = wave * 16 + quad * 4 + r;
            const int col = nt * 16 + lrow;
            op[row * HDIM + col] = acc[nt][r];
        }
    }
}

extern "C" void kernel_launch(void* const* d_in, const int* in_sizes, int n_in,
                              void* d_out, int out_size, void* d_ws, size_t ws_size,
                              hipStream_t stream) {
    const float* s = (const float*)d_in[0];
    const float* v = (const float*)d_in[1];
    float* out = (float*)d_out;
    const int BM = in_sizes[0] / (QTDIM * KVDIM);  // 64
    dim3 grid(BM, QTDIM / QTILE);                  // (64, 8) = 512 blocks, all co-resident
    svbmm_kernel<<<grid, THREADS, 0, stream>>>(s, v, out);
}